// Round 11
// baseline (244.012 us; speedup 1.0000x reference)
//
#include <hip/hip_runtime.h>
#include <cstdint>
#include <cstddef>

// ---------------------------------------------------------------------------
// MHA block: out = proj( causal_softmax( (xWq)(xWk)^T / 8 ) (xWv) )
// B=4, T=2048, C=1024, H=16, D=64.  All GEMM-shaped compute on bf16 MFMA.
// ---------------------------------------------------------------------------

typedef short bf16x8 __attribute__((ext_vector_type(8)));
typedef float f32x4 __attribute__((ext_vector_type(4)));

#define MFMA32(a, b, c) __builtin_amdgcn_mfma_f32_16x16x32_bf16((a), (b), (c), 0, 0, 0)

__device__ __forceinline__ unsigned short f2b(float f) {
  unsigned int x = __builtin_bit_cast(unsigned int, f);
  x += 0x7fffu + ((x >> 16) & 1u);
  return (unsigned short)(x >> 16);
}

__device__ __forceinline__ unsigned int pack2(float a, float b) {
  return (unsigned int)f2b(a) | ((unsigned int)f2b(b) << 16);
}

__device__ __forceinline__ unsigned int cvtpk(float a, float b) {
  unsigned int r;
  asm("v_cvt_pk_bf16_f32 %0, %1, %2" : "=v"(r) : "v"(a), "v"(b));
  return r;
}

__device__ __forceinline__ float exp2v(float x) {
  float r;
  asm("v_exp_f32 %0, %1" : "=v"(r) : "v"(x));
  return r;
}

__device__ __forceinline__ void gload16(const void* g, void* l) {
  __builtin_amdgcn_global_load_lds(
      (const __attribute__((address_space(1))) void*)g,
      (__attribute__((address_space(3))) void*)l, 16, 0, 0);
}

// ---------------------------------------------------------------------------
__global__ __launch_bounds__(256) void k_conv_x(const float* __restrict__ in,
                                                unsigned short* __restrict__ out, int n4) {
  int i = blockIdx.x * 256 + threadIdx.x;
  if (i >= n4) return;
  float4 v = reinterpret_cast<const float4*>(in)[i];
  ushort4 o;
  o.x = f2b(v.x); o.y = f2b(v.y); o.z = f2b(v.z); o.w = f2b(v.w);
  reinterpret_cast<ushort4*>(out)[i] = o;
}

// ---------------------------------------------------------------------------
__global__ __launch_bounds__(256) void k_transpose(const float* __restrict__ in,
                                                   unsigned short* __restrict__ out,
                                                   int R, int C) {
  __shared__ float tile[32][33];
  int c0 = blockIdx.x * 32, r0 = blockIdx.y * 32;
  int tx = threadIdx.x & 31, ty = threadIdx.x >> 5;
#pragma unroll
  for (int j = 0; j < 4; ++j)
    tile[ty + 8 * j][tx] = in[(size_t)(r0 + ty + 8 * j) * C + c0 + tx];
  __syncthreads();
#pragma unroll
  for (int j = 0; j < 4; ++j)
    out[(size_t)(c0 + ty + 8 * j) * R + r0 + tx] = f2b(tile[tx][ty + 8 * j]);
}

// ---------------------------------------------------------------------------
// bf16 GEMM, 128x128 tile, BK=64, 4 waves, 64x64/wave.
// NEW (R11): A-fragments loaded DIRECTLY from global into VGPRs (no A-LDS
//   staging) — A rows are L1/L2-resident and wave-exclusive-ish; this halves
//   the LDS-read-pipe traffic (the measured bottleneck).  B stays LDS-staged
//   with the R9 XOR-swizzle (conflict-free).
// EPI=0: LDS-bounce epilogue -> q/k/v ws.  EPI=1: direct f32 out.
// ---------------------------------------------------------------------------
template <int EPI>
__global__ __launch_bounds__(256) void k_gemm(const unsigned short* __restrict__ A,
                                              const unsigned short* __restrict__ Bt,
                                              float* __restrict__ outF,
                                              unsigned short* __restrict__ q_ws,
                                              unsigned short* __restrict__ k_ws,
                                              unsigned short* __restrict__ v_ws,
                                              int M, int N) {
  constexpr int K = 1024;
  __shared__ unsigned short smem[16384];  // Bs in [0,8192); epilogue uses all 32KB
  unsigned short* Bs = smem;
  const int bn = blockIdx.x, bm = blockIdx.y;
  const int tid = threadIdx.x;
  const int w = tid >> 6, lane = tid & 63;
  const int wm = w >> 1, wn = w & 1;
  const int c = lane & 15, g = lane >> 4;
  const int cl8 = c & 7;

  f32x4 acc[4][4];
#pragma unroll
  for (int i = 0; i < 4; ++i)
#pragma unroll
    for (int j = 0; j < 4; ++j) acc[i][j] = (f32x4){0.f, 0.f, 0.f, 0.f};

  const int srow = 32 * w + (lane >> 3);
  const int scol = 8 * ((lane & 7) ^ (lane >> 3));
  const unsigned short* Bg = Bt + (size_t)(bn * 128 + srow) * K + scol;
  char* BsB = (char*)Bs + w * 4096;

  // per-lane A fragment base: row = bm*128 + wm*64 + mf*16 + c, k = kt*64+u*32+g*8
  const unsigned short* Arow = A + (size_t)(bm * 128 + wm * 64 + c) * K + g * 8;

  for (int kt = 0; kt < K / 64; ++kt) {
    const int kb = kt * 64;
    __syncthreads();  // Bs readers of previous tile done
#pragma unroll
    for (int i = 0; i < 4; ++i)
      gload16(Bg + (size_t)(8 * i) * K + kb, BsB + i * 1024);
    bf16x8 afr[2][4];
#pragma unroll
    for (int u = 0; u < 2; ++u)
#pragma unroll
      for (int mf = 0; mf < 4; ++mf)
        afr[u][mf] = *(const bf16x8*)(Arow + (size_t)(mf * 16) * K + kb + u * 32);
    asm volatile("s_waitcnt vmcnt(0)" ::: "memory");  // B staged + A frags landed
    __syncthreads();
#pragma unroll
    for (int u = 0; u < 2; ++u) {
      bf16x8 bfr[4];
#pragma unroll
      for (int nf = 0; nf < 4; ++nf)
        bfr[nf] = *(const bf16x8*)((const char*)Bs + (wn * 64 + nf * 16 + c) * 128 +
                                   (((u * 4 + g) ^ cl8) * 16));
#pragma unroll
      for (int mf = 0; mf < 4; ++mf)
#pragma unroll
        for (int nf = 0; nf < 4; ++nf)
          acc[mf][nf] = MFMA32(afr[u][mf], bfr[nf], acc[mf][nf]);
    }
  }

  const int rowb = bm * 128 + wm * 64;
  const int colb = bn * 128 + wn * 64;
  if (EPI == 1) {
#pragma unroll
    for (int mf = 0; mf < 4; ++mf)
#pragma unroll
      for (int nf = 0; nf < 4; ++nf)
#pragma unroll
        for (int r = 0; r < 4; ++r) {
          int row = rowb + mf * 16 + 4 * g + r;
          int col = colb + nf * 16 + c;
          outF[(size_t)row * N + col] = acc[mf][nf][r];
        }
  } else {
    const int sec = colb >> 10;
    const int hh = (colb & 1023) >> 6;
    const int b = rowb >> 11, t0 = rowb & 2047;
    unsigned short* Lw = smem + w * 4096;

    __syncthreads();
    if (sec < 2) {
      const float sc = (sec == 0) ? 0.125f * 1.4426950408889634f : 1.f;
#pragma unroll
      for (int mf = 0; mf < 4; ++mf)
#pragma unroll
        for (int nf = 0; nf < 4; ++nf)
#pragma unroll
          for (int r = 0; r < 4; ++r)
            Lw[(16 * mf + 4 * g + r) * 64 + 16 * nf + c] = f2b(acc[mf][nf][r] * sc);
    } else {
#pragma unroll
      for (int mf = 0; mf < 4; ++mf)
#pragma unroll
        for (int nf = 0; nf < 4; ++nf)
#pragma unroll
          for (int rr = 0; rr < 2; ++rr)
            *(unsigned int*)&Lw[(16 * nf + c) * 64 + 16 * mf + 4 * g + 2 * rr] =
                pack2(acc[mf][nf][2 * rr], acc[mf][nf][2 * rr + 1]);
    }
    asm volatile("s_waitcnt lgkmcnt(0)" ::: "memory");
    const int rw = lane >> 3, ch = lane & 7;
    const int chx = ch ^ rw;
    if (sec == 0) {
      unsigned short* dst = q_ws + ((size_t)(b * 16 + hh) * 2048 + t0) * 64;
#pragma unroll
      for (int i = 0; i < 8; ++i) {
        int tl = i * 8 + rw;
        *(bf16x8*)(dst + (size_t)tl * 64 + ch * 8) = *(const bf16x8*)&Lw[tl * 64 + ch * 8];
      }
    } else if (sec == 1) {
      unsigned short* dst = k_ws + ((size_t)(b * 16 + hh) * 2048 + t0) * 64;
#pragma unroll
      for (int i = 0; i < 8; ++i) {
        int tl = i * 8 + rw;
        *(bf16x8*)(dst + (size_t)tl * 64 + chx * 8) = *(const bf16x8*)&Lw[tl * 64 + ch * 8];
      }
    } else {
      unsigned short* dst = v_ws + (size_t)(b * 16 + hh) * 64 * 2048 + t0;
#pragma unroll
      for (int i = 0; i < 8; ++i) {
        int dl = i * 8 + rw;
        *(bf16x8*)(dst + (size_t)dl * 2048 + chx * 8) = *(const bf16x8*)&Lw[dl * 64 + ch * 8];
      }
    }
  }
}

// ---------------------------------------------------------------------------
// Flash attention, causal. 512 blocks x 512 threads (8 waves).  Exact R9
// version (best measured ~80us): 16 q-rows/wave, 2 blocks/CU = 16 waves/CU,
// double-buffered K/V, counted vmcnt(2) + raw s_barrier, swapped QK^T,
// defer-max, cvt_pk packing, setprio around MFMA.
// ---------------------------------------------------------------------------
__global__ __launch_bounds__(512) void k_attn(const unsigned short* __restrict__ q_ws,
                                              const unsigned short* __restrict__ k_ws,
                                              const unsigned short* __restrict__ v_ws,
                                              unsigned short* __restrict__ y_ws) {
  constexpr int T = 2048;
  __shared__ unsigned short Ks[2][64 * 64];
  __shared__ unsigned short Vs[2][64 * 64];
  const int f = blockIdx.x;
  const int f2 = (f & 7) * 64 + (f >> 3);
  const int bh = f2 >> 3;
  const int xi = f2 & 7;
  const int tid = threadIdx.x, w = tid >> 6, lane = tid & 63;
  const int c = lane & 15, g = lane >> 4;
  const int cl = c & 7;
  const size_t base = (size_t)bh * T * 64;
  const unsigned short* Kb = k_ws + base;
  const unsigned short* Vb = v_ws + base;
  const unsigned short* Qb = q_ws + base;

  const int srow = w * 8 + (lane >> 3);
  const int sch = lane & 7;

#pragma unroll 1
  for (int ph = 0; ph < 2; ++ph) {
    const int q0 = (ph == 0 ? xi : 15 - xi) * 128;
    const int qrow = q0 + 16 * w + c;
    const int q_max_wave = q0 + 16 * w + 15;
    const int n_kt = (q0 >> 6) + 2;
    bf16x8 qf[2];
#pragma unroll
    for (int u = 0; u < 2; ++u)
      qf[u] = *(const bf16x8*)(Qb + (size_t)qrow * 64 + 32 * u + 8 * g);

    f32x4 yacc[4];
#pragma unroll
    for (int i = 0; i < 4; ++i) yacc[i] = (f32x4){0.f, 0.f, 0.f, 0.f};
    float m_run = -1e30f, l_part = 0.f;

    __syncthreads();  // prior phase fully done before restaging buf 0
    gload16(Kb + (size_t)srow * 64 + sch * 8, (char*)&Ks[0][0] + w * 1024);
    gload16(Vb + (size_t)srow * T + sch * 8, (char*)&Vs[0][0] + w * 1024);

#pragma unroll 1
    for (int kt = 0; kt < n_kt; ++kt) {
      const int k0 = kt * 64;
      const int cur = kt & 1;
      if (kt + 1 < n_kt) {
        const int k0n = k0 + 64;
        gload16(Kb + (size_t)(k0n + srow) * 64 + sch * 8, (char*)&Ks[cur ^ 1][0] + w * 1024);
        gload16(Vb + (size_t)srow * T + k0n + sch * 8, (char*)&Vs[cur ^ 1][0] + w * 1024);
        asm volatile("s_waitcnt vmcnt(2)" ::: "memory");
      } else {
        asm volatile("s_waitcnt vmcnt(0)" ::: "memory");
      }
      __builtin_amdgcn_s_barrier();

      if (k0 <= q_max_wave) {
        const char* KsC = (const char*)&Ks[cur][0];
        const char* VsC = (const char*)&Vs[cur][0];
        f32x4 s[4];
        __builtin_amdgcn_s_setprio(1);
#pragma unroll
        for (int tf = 0; tf < 4; ++tf) {
          bf16x8 kf0 = *(const bf16x8*)(KsC + (16 * tf + c) * 128 + (g ^ cl) * 16);
          bf16x8 kf1 = *(const bf16x8*)(KsC + (16 * tf + c) * 128 + ((4 + g) ^ cl) * 16);
          f32x4 z = (f32x4){0.f, 0.f, 0.f, 0.f};
          z = MFMA32(kf0, qf[0], z);
          s[tf] = MFMA32(kf1, qf[1], z);
        }
        __builtin_amdgcn_s_setprio(0);
        if (k0 + 63 > q0 + 16 * w) {
#pragma unroll
          for (int tf = 0; tf < 4; ++tf)
#pragma unroll
            for (int r = 0; r < 4; ++r)
              if (k0 + 16 * tf + 4 * g + r > qrow) s[tf][r] = -1e30f;
        }
        float mx0 = fmaxf(fmaxf(s[0][0], s[0][1]), fmaxf(s[0][2], s[0][3]));
        float mx1 = fmaxf(fmaxf(s[1][0], s[1][1]), fmaxf(s[1][2], s[1][3]));
        float mx2 = fmaxf(fmaxf(s[2][0], s[2][1]), fmaxf(s[2][2], s[2][3]));
        float mx3 = fmaxf(fmaxf(s[3][0], s[3][1]), fmaxf(s[3][2], s[3][3]));
        float mx = fmaxf(fmaxf(mx0, mx1), fmaxf(mx2, mx3));
        mx = fmaxf(mx, __shfl_xor(mx, 16));
        mx = fmaxf(mx, __shfl_xor(mx, 32));
        if (__any(mx > m_run + 11.5f)) {
          float m_new = fmaxf(m_run, mx);
          float corr = exp2v(m_run - m_new);
          l_part *= corr;
#pragma unroll
          for (int i = 0; i < 4; ++i) yacc[i] *= corr;
          m_run = m_new;
        }
        float p[16];
#pragma unroll
        for (int tf = 0; tf < 4; ++tf)
#pragma unroll
          for (int r = 0; r < 4; ++r) p[tf * 4 + r] = exp2v(s[tf][r] - m_run);
        float ps = ((p[0] + p[1]) + (p[2] + p[3])) + ((p[4] + p[5]) + (p[6] + p[7]));
        ps += ((p[8] + p[9]) + (p[10] + p[11])) + ((p[12] + p[13]) + (p[14] + p[15]));
        l_part += ps;

#pragma unroll
        for (int h = 0; h < 2; ++h) {
          unsigned int lo0 = cvtpk(p[8 * h + 0], p[8 * h + 1]);
          unsigned int hi0 = cvtpk(p[8 * h + 2], p[8 * h + 3]);
          unsigned int lo1 = cvtpk(p[8 * h + 4], p[8 * h + 5]);
          unsigned int hi1 = cvtpk(p[8 * h + 6], p[8 * h + 7]);
          int a2 = 2 * (g & 1);
          int srcA = 16 * a2 + c, srcB = srcA + 16;
          unsigned int Al0 = __shfl(lo0, srcA), Ah0 = __shfl(hi0, srcA);
          unsigned int Al1 = __shfl(lo1, srcA), Ah1 = __shfl(hi1, srcA);
          unsigned int Bl0 = __shfl(lo0, srcB), Bh0 = __shfl(hi0, srcB);
          unsigned int Bl1 = __shfl(lo1, srcB), Bh1 = __shfl(hi1, srcB);
          bool f1 = (g >= 2);
          union { unsigned int u[4]; bf16x8 v; } pf;
          pf.u[0] = f1 ? Al1 : Al0;
          pf.u[1] = f1 ? Ah1 : Ah0;
          pf.u[2] = f1 ? Bl1 : Bl0;
          pf.u[3] = f1 ? Bh1 : Bh0;
          __builtin_amdgcn_s_setprio(1);
#pragma unroll
          for (int df = 0; df < 4; ++df) {
            bf16x8 vf = *(const bf16x8*)(VsC + (16 * df + c) * 128 + ((h * 4 + g) ^ cl) * 16);
            yacc[df] = MFMA32(vf, pf.v, yacc[df]);
          }
          __builtin_amdgcn_s_setprio(0);
        }
      }
      __builtin_amdgcn_s_barrier();
    }

    float lt = l_part;
    lt += __shfl_xor(lt, 16);
    lt += __shfl_xor(lt, 32);
    float inv = 1.f / lt;
    const int b = bh >> 4, hh = bh & 15;
#pragma unroll
    for (int df = 0; df < 4; ++df) {
      uint2 o;
      o.x = cvtpk(yacc[df][0] * inv, yacc[df][1] * inv);
      o.y = cvtpk(yacc[df][2] * inv, yacc[df][3] * inv);
      *(uint2*)(y_ws + (size_t)(b * 2048 + qrow) * 1024 + hh * 64 + 16 * df + 4 * g) = o;
    }
  }
}

// ---------------------------------------------------------------------------
extern "C" void kernel_launch(void* const* d_in, const int* in_sizes, int n_in,
                              void* d_out, int out_size, void* d_ws, size_t ws_size,
                              hipStream_t stream) {
  const float* x = (const float*)d_in[0];      // (4, 2048, 1024)
  const float* Wqkv = (const float*)d_in[1];   // (1024, 3072)
  const float* Wproj = (const float*)d_in[2];  // (1024, 1024)
  float* out = (float*)d_out;                  // (4, 2048, 1024)
  char* ws = (char*)d_ws;

  unsigned short* x_bf = (unsigned short*)(ws);                    // 16 MiB
  unsigned short* wqkvT = (unsigned short*)(ws + 16777216);        // 6 MiB
  unsigned short* wprojT = (unsigned short*)(ws + 23068672);       // 2 MiB
  unsigned short* q_ws = (unsigned short*)(ws + 25165824);         // 16 MiB
  unsigned short* k_ws = (unsigned short*)(ws + 41943040);         // 16 MiB
  unsigned short* v_ws = (unsigned short*)(ws + 58720256);         // 16 MiB
  unsigned short* y_ws = (unsigned short*)(ws + 75497472);         // 16 MiB

  k_conv_x<<<8192, 256, 0, stream>>>(x, x_bf, 2097152);
  k_transpose<<<dim3(96, 32), 256, 0, stream>>>(Wqkv, wqkvT, 1024, 3072);
  k_transpose<<<dim3(32, 32), 256, 0, stream>>>(Wproj, wprojT, 1024, 1024);
  k_gemm<0><<<dim3(24, 64), 256, 0, stream>>>(x_bf, wqkvT, nullptr, q_ws, k_ws, v_ws, 8192, 3072);
  k_attn<<<512, 512, 0, stream>>>(q_ws, k_ws, v_ws, y_ws);
  k_gemm<1><<<dim3(8, 64), 256, 0, stream>>>(y_ws, wprojT, out, nullptr, nullptr, nullptr, 8192, 1024);
}

// Round 13
// 197.911 us; speedup vs baseline: 1.2329x; 1.2329x over previous
//
#include <hip/hip_runtime.h>
#include <cstdint>
#include <cstddef>

// ---------------------------------------------------------------------------
// MHA block: out = proj( causal_softmax( (xWq)(xWk)^T / 8 ) (xWv) )
// B=4, T=2048, C=1024, H=16, D=64.  All GEMM-shaped compute on bf16 MFMA.
// ---------------------------------------------------------------------------

typedef short bf16x8 __attribute__((ext_vector_type(8)));
typedef float f32x4 __attribute__((ext_vector_type(4)));

#define MFMA32(a, b, c) __builtin_amdgcn_mfma_f32_16x16x32_bf16((a), (b), (c), 0, 0, 0)

__device__ __forceinline__ unsigned short f2b(float f) {
  unsigned int x = __builtin_bit_cast(unsigned int, f);
  x += 0x7fffu + ((x >> 16) & 1u);
  return (unsigned short)(x >> 16);
}

__device__ __forceinline__ unsigned int pack2(float a, float b) {
  return (unsigned int)f2b(a) | ((unsigned int)f2b(b) << 16);
}

__device__ __forceinline__ unsigned int cvtpk(float a, float b) {
  unsigned int r;
  asm("v_cvt_pk_bf16_f32 %0, %1, %2" : "=v"(r) : "v"(a), "v"(b));
  return r;
}

__device__ __forceinline__ float exp2v(float x) {
  float r;
  asm("v_exp_f32 %0, %1" : "=v"(r) : "v"(x));
  return r;
}

__device__ __forceinline__ void gload16(const void* g, void* l) {
  __builtin_amdgcn_global_load_lds(
      (const __attribute__((address_space(1))) void*)g,
      (__attribute__((address_space(3))) void*)l, 16, 0, 0);
}

// ---------------------------------------------------------------------------
__global__ __launch_bounds__(256) void k_conv_x(const float* __restrict__ in,
                                                unsigned short* __restrict__ out, int n4) {
  int i = blockIdx.x * 256 + threadIdx.x;
  if (i >= n4) return;
  float4 v = reinterpret_cast<const float4*>(in)[i];
  ushort4 o;
  o.x = f2b(v.x); o.y = f2b(v.y); o.z = f2b(v.z); o.w = f2b(v.w);
  reinterpret_cast<ushort4*>(out)[i] = o;
}

// ---------------------------------------------------------------------------
__global__ __launch_bounds__(256) void k_transpose(const float* __restrict__ in,
                                                   unsigned short* __restrict__ out,
                                                   int R, int C) {
  __shared__ float tile[32][33];
  int c0 = blockIdx.x * 32, r0 = blockIdx.y * 32;
  int tx = threadIdx.x & 31, ty = threadIdx.x >> 5;
#pragma unroll
  for (int j = 0; j < 4; ++j)
    tile[ty + 8 * j][tx] = in[(size_t)(r0 + ty + 8 * j) * C + c0 + tx];
  __syncthreads();
#pragma unroll
  for (int j = 0; j < 4; ++j)
    out[(size_t)(c0 + ty + 8 * j) * R + r0 + tx] = f2b(tile[tx][ty + 8 * j]);
}

// ---------------------------------------------------------------------------
// bf16 GEMM (R9 mainloop: m97 + both-sides LDS XOR-swizzle, conflict-free).
// NEW (R13): XCD-chunked block remap, bm-fastest within chunk — each XCD
//   keeps its 1-3 B-panels L2-resident; A streams via L3 (cuts HBM refetch).
// EPI=0: LDS-bounce epilogue -> q/k/v ws.  EPI=1: direct f32 out.
// ---------------------------------------------------------------------------
template <int EPI>
__global__ __launch_bounds__(256) void k_gemm(const unsigned short* __restrict__ A,
                                              const unsigned short* __restrict__ Bt,
                                              float* __restrict__ outF,
                                              unsigned short* __restrict__ q_ws,
                                              unsigned short* __restrict__ k_ws,
                                              unsigned short* __restrict__ v_ws,
                                              int M, int N) {
  constexpr int K = 1024;
  __shared__ unsigned short smem[16384];  // As | Bs; epilogue reuses
  unsigned short* As = smem;
  unsigned short* Bs = smem + 8192;
  // XCD-chunked remap (gridDim.y == 64, nwg % 8 == 0): XCD x owns a
  // contiguous idx chunk; bm varies fastest -> B-panels stay hot in its L2.
  const int f = blockIdx.x + blockIdx.y * gridDim.x;
  const int cpx = (gridDim.x * gridDim.y) >> 3;
  const int idx = (f & 7) * cpx + (f >> 3);
  const int bm = idx & 63;
  const int bn = idx >> 6;
  const int tid = threadIdx.x;
  const int w = tid >> 6, lane = tid & 63;
  const int wm = w >> 1, wn = w & 1;
  const int c = lane & 15, g = lane >> 4;
  const int cl8 = c & 7;

  f32x4 acc[4][4];
#pragma unroll
  for (int i = 0; i < 4; ++i)
#pragma unroll
    for (int j = 0; j < 4; ++j) acc[i][j] = (f32x4){0.f, 0.f, 0.f, 0.f};

  const int srow = 32 * w + (lane >> 3);
  const int scol = 8 * ((lane & 7) ^ (lane >> 3));
  const unsigned short* Ag = A + (size_t)(bm * 128 + srow) * K + scol;
  const unsigned short* Bg = Bt + (size_t)(bn * 128 + srow) * K + scol;
  char* AsB = (char*)As + w * 4096;
  char* BsB = (char*)Bs + w * 4096;

  for (int kt = 0; kt < K / 64; ++kt) {
    const int kb = kt * 64;
    __syncthreads();
#pragma unroll
    for (int i = 0; i < 4; ++i) {
      gload16(Ag + (size_t)(8 * i) * K + kb, AsB + i * 1024);
      gload16(Bg + (size_t)(8 * i) * K + kb, BsB + i * 1024);
    }
    asm volatile("s_waitcnt vmcnt(0)" ::: "memory");
    __syncthreads();
#pragma unroll
    for (int u = 0; u < 2; ++u) {
      bf16x8 af[4], bfr[4];
#pragma unroll
      for (int mf = 0; mf < 4; ++mf)
        af[mf] = *(const bf16x8*)((const char*)As + (wm * 64 + mf * 16 + c) * 128 +
                                  (((u * 4 + g) ^ cl8) * 16));
#pragma unroll
      for (int nf = 0; nf < 4; ++nf)
        bfr[nf] = *(const bf16x8*)((const char*)Bs + (wn * 64 + nf * 16 + c) * 128 +
                                   (((u * 4 + g) ^ cl8) * 16));
#pragma unroll
      for (int mf = 0; mf < 4; ++mf)
#pragma unroll
        for (int nf = 0; nf < 4; ++nf)
          acc[mf][nf] = MFMA32(af[mf], bfr[nf], acc[mf][nf]);
    }
  }

  const int rowb = bm * 128 + wm * 64;
  const int colb = bn * 128 + wn * 64;
  if (EPI == 1) {
#pragma unroll
    for (int mf = 0; mf < 4; ++mf)
#pragma unroll
      for (int nf = 0; nf < 4; ++nf)
#pragma unroll
        for (int r = 0; r < 4; ++r) {
          int row = rowb + mf * 16 + 4 * g + r;
          int col = colb + nf * 16 + c;
          outF[(size_t)row * N + col] = acc[mf][nf][r];
        }
  } else {
    const int sec = colb >> 10;
    const int hh = (colb & 1023) >> 6;
    const int b = rowb >> 11, t0 = rowb & 2047;
    unsigned short* Lw = smem + w * 4096;

    __syncthreads();
    if (sec < 2) {
      const float sc = (sec == 0) ? 0.125f * 1.4426950408889634f : 1.f;
#pragma unroll
      for (int mf = 0; mf < 4; ++mf)
#pragma unroll
        for (int nf = 0; nf < 4; ++nf)
#pragma unroll
          for (int r = 0; r < 4; ++r)
            Lw[(16 * mf + 4 * g + r) * 64 + 16 * nf + c] = f2b(acc[mf][nf][r] * sc);
    } else {
#pragma unroll
      for (int mf = 0; mf < 4; ++mf)
#pragma unroll
        for (int nf = 0; nf < 4; ++nf)
#pragma unroll
          for (int rr = 0; rr < 2; ++rr)
            *(unsigned int*)&Lw[(16 * nf + c) * 64 + 16 * mf + 4 * g + 2 * rr] =
                pack2(acc[mf][nf][2 * rr], acc[mf][nf][2 * rr + 1]);
    }
    asm volatile("s_waitcnt lgkmcnt(0)" ::: "memory");
    const int rw = lane >> 3, ch = lane & 7;
    const int chx = ch ^ rw;
    if (sec == 0) {
      unsigned short* dst = q_ws + ((size_t)(b * 16 + hh) * 2048 + t0) * 64;
#pragma unroll
      for (int i = 0; i < 8; ++i) {
        int tl = i * 8 + rw;
        *(bf16x8*)(dst + (size_t)tl * 64 + ch * 8) = *(const bf16x8*)&Lw[tl * 64 + ch * 8];
      }
    } else if (sec == 1) {
      unsigned short* dst = k_ws + ((size_t)(b * 16 + hh) * 2048 + t0) * 64;
#pragma unroll
      for (int i = 0; i < 8; ++i) {
        int tl = i * 8 + rw;
        *(bf16x8*)(dst + (size_t)tl * 64 + chx * 8) = *(const bf16x8*)&Lw[tl * 64 + ch * 8];
      }
    } else {
      unsigned short* dst = v_ws + (size_t)(b * 16 + hh) * 64 * 2048 + t0;
#pragma unroll
      for (int i = 0; i < 8; ++i) {
        int dl = i * 8 + rw;
        *(bf16x8*)(dst + (size_t)dl * 2048 + chx * 8) = *(const bf16x8*)&Lw[dl * 64 + ch * 8];
      }
    }
  }
}

// ---------------------------------------------------------------------------
// Flash attention, causal. 512 blocks x 512 threads (8 waves), R9 compute.
// NEW (R13): 3-buffer, 2-DEEP K/V staging pipeline — prologue stages kt=0,1;
// each iteration stages kt+2 with counted vmcnt(4) (tail 2 -> 0).  Buffer
// reuse distance 3 > read horizon; every pair confirmed by own-wave vmcnt +
// barrier before first read.  Compute section identical to R9 (proven).
// ---------------------------------------------------------------------------
__global__ __launch_bounds__(512) void k_attn(const unsigned short* __restrict__ q_ws,
                                              const unsigned short* __restrict__ k_ws,
                                              const unsigned short* __restrict__ v_ws,
                                              unsigned short* __restrict__ y_ws) {
  constexpr int T = 2048;
  __shared__ unsigned short Ks[3][64 * 64];  // 3 x 8KB
  __shared__ unsigned short Vs[3][64 * 64];  // 3 x 8KB
  const int f = blockIdx.x;
  const int f2 = (f & 7) * 64 + (f >> 3);
  const int bh = f2 >> 3;
  const int xi = f2 & 7;
  const int tid = threadIdx.x, w = tid >> 6, lane = tid & 63;
  const int c = lane & 15, g = lane >> 4;
  const int cl = c & 7;
  const size_t base = (size_t)bh * T * 64;
  const unsigned short* Kb = k_ws + base;
  const unsigned short* Vb = v_ws + base;
  const unsigned short* Qb = q_ws + base;

  const int srow = w * 8 + (lane >> 3);
  const int sch = lane & 7;

#pragma unroll 1
  for (int ph = 0; ph < 2; ++ph) {
    const int q0 = (ph == 0 ? xi : 15 - xi) * 128;
    const int qrow = q0 + 16 * w + c;
    const int q_max_wave = q0 + 16 * w + 15;
    const int n_kt = (q0 >> 6) + 2;  // >= 2 always
    bf16x8 qf[2];
#pragma unroll
    for (int u = 0; u < 2; ++u)
      qf[u] = *(const bf16x8*)(Qb + (size_t)qrow * 64 + 32 * u + 8 * g);

    f32x4 yacc[4];
#pragma unroll
    for (int i = 0; i < 4; ++i) yacc[i] = (f32x4){0.f, 0.f, 0.f, 0.f};
    float m_run = -1e30f, l_part = 0.f;

    __syncthreads();  // prior phase fully done (drains all counts) before restage
    // prologue: stage kt=0 -> buf0, kt=1 -> buf1
    gload16(Kb + (size_t)srow * 64 + sch * 8, (char*)&Ks[0][0] + w * 1024);
    gload16(Vb + (size_t)srow * T + sch * 8, (char*)&Vs[0][0] + w * 1024);
    gload16(Kb + (size_t)(64 + srow) * 64 + sch * 8, (char*)&Ks[1][0] + w * 1024);
    gload16(Vb + (size_t)srow * T + 64 + sch * 8, (char*)&Vs[1][0] + w * 1024);

    int cur = 0;
#pragma unroll 1
    for (int kt = 0; kt < n_kt; ++kt) {
      const int k0 = kt * 64;
      if (kt + 2 < n_kt) {  // stage kt+2 two tiles ahead
        int nx2 = cur + 2;
        if (nx2 >= 3) nx2 -= 3;
        const int k0n = k0 + 128;
        gload16(Kb + (size_t)(k0n + srow) * 64 + sch * 8, (char*)&Ks[nx2][0] + w * 1024);
        gload16(Vb + (size_t)srow * T + k0n + sch * 8, (char*)&Vs[nx2][0] + w * 1024);
        asm volatile("s_waitcnt vmcnt(4)" ::: "memory");  // pair(kt) landed
      } else if (kt + 1 < n_kt) {
        asm volatile("s_waitcnt vmcnt(2)" ::: "memory");  // pair(kt) landed
      } else {
        asm volatile("s_waitcnt vmcnt(0)" ::: "memory");
      }
      __builtin_amdgcn_s_barrier();  // all waves' pair(kt) visible

      if (k0 <= q_max_wave) {
        const char* KsC = (const char*)&Ks[cur][0];
        const char* VsC = (const char*)&Vs[cur][0];
        f32x4 s[4];
        __builtin_amdgcn_s_setprio(1);
#pragma unroll
        for (int tf = 0; tf < 4; ++tf) {
          bf16x8 kf0 = *(const bf16x8*)(KsC + (16 * tf + c) * 128 + (g ^ cl) * 16);
          bf16x8 kf1 = *(const bf16x8*)(KsC + (16 * tf + c) * 128 + ((4 + g) ^ cl) * 16);
          f32x4 z = (f32x4){0.f, 0.f, 0.f, 0.f};
          z = MFMA32(kf0, qf[0], z);
          s[tf] = MFMA32(kf1, qf[1], z);
        }
        __builtin_amdgcn_s_setprio(0);
        if (k0 + 63 > q0 + 16 * w) {
#pragma unroll
          for (int tf = 0; tf < 4; ++tf)
#pragma unroll
            for (int r = 0; r < 4; ++r)
              if (k0 + 16 * tf + 4 * g + r > qrow) s[tf][r] = -1e30f;
        }
        float mx0 = fmaxf(fmaxf(s[0][0], s[0][1]), fmaxf(s[0][2], s[0][3]));
        float mx1 = fmaxf(fmaxf(s[1][0], s[1][1]), fmaxf(s[1][2], s[1][3]));
        float mx2 = fmaxf(fmaxf(s[2][0], s[2][1]), fmaxf(s[2][2], s[2][3]));
        float mx3 = fmaxf(fmaxf(s[3][0], s[3][1]), fmaxf(s[3][2], s[3][3]));
        float mx = fmaxf(fmaxf(mx0, mx1), fmaxf(mx2, mx3));
        mx = fmaxf(mx, __shfl_xor(mx, 16));
        mx = fmaxf(mx, __shfl_xor(mx, 32));
        if (__any(mx > m_run + 11.5f)) {
          float m_new = fmaxf(m_run, mx);
          float corr = exp2v(m_run - m_new);
          l_part *= corr;
#pragma unroll
          for (int i = 0; i < 4; ++i) yacc[i] *= corr;
          m_run = m_new;
        }
        float p[16];
#pragma unroll
        for (int tf = 0; tf < 4; ++tf)
#pragma unroll
          for (int r = 0; r < 4; ++r) p[tf * 4 + r] = exp2v(s[tf][r] - m_run);
        float ps = ((p[0] + p[1]) + (p[2] + p[3])) + ((p[4] + p[5]) + (p[6] + p[7]));
        ps += ((p[8] + p[9]) + (p[10] + p[11])) + ((p[12] + p[13]) + (p[14] + p[15]));
        l_part += ps;

#pragma unroll
        for (int h = 0; h < 2; ++h) {
          unsigned int lo0 = cvtpk(p[8 * h + 0], p[8 * h + 1]);
          unsigned int hi0 = cvtpk(p[8 * h + 2], p[8 * h + 3]);
          unsigned int lo1 = cvtpk(p[8 * h + 4], p[8 * h + 5]);
          unsigned int hi1 = cvtpk(p[8 * h + 6], p[8 * h + 7]);
          int a2 = 2 * (g & 1);
          int srcA = 16 * a2 + c, srcB = srcA + 16;
          unsigned int Al0 = __shfl(lo0, srcA), Ah0 = __shfl(hi0, srcA);
          unsigned int Al1 = __shfl(lo1, srcA), Ah1 = __shfl(hi1, srcA);
          unsigned int Bl0 = __shfl(lo0, srcB), Bh0 = __shfl(hi0, srcB);
          unsigned int Bl1 = __shfl(lo1, srcB), Bh1 = __shfl(hi1, srcB);
          bool f1 = (g >= 2);
          union { unsigned int u[4]; bf16x8 v; } pf;
          pf.u[0] = f1 ? Al1 : Al0;
          pf.u[1] = f1 ? Ah1 : Ah0;
          pf.u[2] = f1 ? Bl1 : Bl0;
          pf.u[3] = f1 ? Bh1 : Bh0;
          __builtin_amdgcn_s_setprio(1);
#pragma unroll
          for (int df = 0; df < 4; ++df) {
            bf16x8 vf = *(const bf16x8*)(VsC + (16 * df + c) * 128 + ((h * 4 + g) ^ cl) * 16);
            yacc[df] = MFMA32(vf, pf.v, yacc[df]);
          }
          __builtin_amdgcn_s_setprio(0);
        }
      }
      __builtin_amdgcn_s_barrier();  // readers done before buf reuse (dist 3)
      cur = (cur + 1 == 3) ? 0 : cur + 1;
    }

    float lt = l_part;
    lt += __shfl_xor(lt, 16);
    lt += __shfl_xor(lt, 32);
    float inv = 1.f / lt;
    const int b = bh >> 4, hh = bh & 15;
#pragma unroll
    for (int df = 0; df < 4; ++df) {
      uint2 o;
      o.x = cvtpk(yacc[df][0] * inv, yacc[df][1] * inv);
      o.y = cvtpk(yacc[df][2] * inv, yacc[df][3] * inv);
      *(uint2*)(y_ws + (size_t)(b * 2048 + qrow) * 1024 + hh * 64 + 16 * df + 4 * g) = o;
    }
  }
}

// ---------------------------------------------------------------------------
extern "C" void kernel_launch(void* const* d_in, const int* in_sizes, int n_in,
                              void* d_out, int out_size, void* d_ws, size_t ws_size,
                              hipStream_t stream) {
  const float* x = (const float*)d_in[0];      // (4, 2048, 1024)
  const float* Wqkv = (const float*)d_in[1];   // (1024, 3072)
  const float* Wproj = (const float*)d_in[2];  // (1024, 1024)
  float* out = (float*)d_out;                  // (4, 2048, 1024)
  char* ws = (char*)d_ws;

  unsigned short* x_bf = (unsigned short*)(ws);                    // 16 MiB
  unsigned short* wqkvT = (unsigned short*)(ws + 16777216);        // 6 MiB
  unsigned short* wprojT = (unsigned short*)(ws + 23068672);       // 2 MiB
  unsigned short* q_ws = (unsigned short*)(ws + 25165824);         // 16 MiB
  unsigned short* k_ws = (unsigned short*)(ws + 41943040);         // 16 MiB
  unsigned short* v_ws = (unsigned short*)(ws + 58720256);         // 16 MiB
  unsigned short* y_ws = (unsigned short*)(ws + 75497472);         // 16 MiB

  k_conv_x<<<8192, 256, 0, stream>>>(x, x_bf, 2097152);
  k_transpose<<<dim3(96, 32), 256, 0, stream>>>(Wqkv, wqkvT, 1024, 3072);
  k_transpose<<<dim3(32, 32), 256, 0, stream>>>(Wproj, wprojT, 1024, 1024);
  k_gemm<0><<<dim3(24, 64), 256, 0, stream>>>(x_bf, wqkvT, nullptr, q_ws, k_ws, v_ws, 8192, 3072);
  k_attn<<<512, 512, 0, stream>>>(q_ws, k_ws, v_ws, y_ws);
  k_gemm<1><<<dim3(8, 64), 256, 0, stream>>>(y_ws, wprojT, out, nullptr, nullptr, nullptr, 8192, 1024);
}

// Round 14
// 184.528 us; speedup vs baseline: 1.3224x; 1.0725x over previous
//
#include <hip/hip_runtime.h>
#include <cstdint>
#include <cstddef>

// ---------------------------------------------------------------------------
// MHA block: out = proj( causal_softmax( (xWq)(xWk)^T / 8 ) (xWv) )
// B=4, T=2048, C=1024, H=16, D=64.  All GEMM-shaped compute on bf16 MFMA.
// ---------------------------------------------------------------------------

typedef short bf16x8 __attribute__((ext_vector_type(8)));
typedef float f32x4 __attribute__((ext_vector_type(4)));

#define MFMA32(a, b, c) __builtin_amdgcn_mfma_f32_16x16x32_bf16((a), (b), (c), 0, 0, 0)

__device__ __forceinline__ unsigned short f2b(float f) {
  unsigned int x = __builtin_bit_cast(unsigned int, f);
  x += 0x7fffu + ((x >> 16) & 1u);
  return (unsigned short)(x >> 16);
}

__device__ __forceinline__ unsigned int pack2(float a, float b) {
  return (unsigned int)f2b(a) | ((unsigned int)f2b(b) << 16);
}

__device__ __forceinline__ unsigned int cvtpk(float a, float b) {
  unsigned int r;
  asm("v_cvt_pk_bf16_f32 %0, %1, %2" : "=v"(r) : "v"(a), "v"(b));
  return r;
}

__device__ __forceinline__ float exp2v(float x) {
  float r;
  asm("v_exp_f32 %0, %1" : "=v"(r) : "v"(x));
  return r;
}

__device__ __forceinline__ void gload16(const void* g, void* l) {
  __builtin_amdgcn_global_load_lds(
      (const __attribute__((address_space(1))) void*)g,
      (__attribute__((address_space(3))) void*)l, 16, 0, 0);
}

// ---------------------------------------------------------------------------
__global__ __launch_bounds__(256) void k_conv_x(const float* __restrict__ in,
                                                unsigned short* __restrict__ out, int n4) {
  int i = blockIdx.x * 256 + threadIdx.x;
  if (i >= n4) return;
  float4 v = reinterpret_cast<const float4*>(in)[i];
  ushort4 o;
  o.x = f2b(v.x); o.y = f2b(v.y); o.z = f2b(v.z); o.w = f2b(v.w);
  reinterpret_cast<ushort4*>(out)[i] = o;
}

// ---------------------------------------------------------------------------
__global__ __launch_bounds__(256) void k_transpose(const float* __restrict__ in,
                                                   unsigned short* __restrict__ out,
                                                   int R, int C) {
  __shared__ float tile[32][33];
  int c0 = blockIdx.x * 32, r0 = blockIdx.y * 32;
  int tx = threadIdx.x & 31, ty = threadIdx.x >> 5;
#pragma unroll
  for (int j = 0; j < 4; ++j)
    tile[ty + 8 * j][tx] = in[(size_t)(r0 + ty + 8 * j) * C + c0 + tx];
  __syncthreads();
#pragma unroll
  for (int j = 0; j < 4; ++j)
    out[(size_t)(c0 + ty + 8 * j) * R + r0 + tx] = f2b(tile[tx][ty + 8 * j]);
}

// ---------------------------------------------------------------------------
// bf16 GEMM (exact R9: m97 mainloop + both-sides LDS XOR-swizzle, conflict-
// free ds_reads; DEFAULT dispatch order — R13's remap refuted, 200MB fetch).
// 128x128 tile, BK=64, 4 waves, 64x64/wave.
// EPI=0: LDS-bounce epilogue -> q/k/v ws.  EPI=1: direct f32 out.
// ---------------------------------------------------------------------------
template <int EPI>
__global__ __launch_bounds__(256) void k_gemm(const unsigned short* __restrict__ A,
                                              const unsigned short* __restrict__ Bt,
                                              float* __restrict__ outF,
                                              unsigned short* __restrict__ q_ws,
                                              unsigned short* __restrict__ k_ws,
                                              unsigned short* __restrict__ v_ws,
                                              int M, int N) {
  constexpr int K = 1024;
  __shared__ unsigned short smem[16384];  // As | Bs; epilogue reuses
  unsigned short* As = smem;
  unsigned short* Bs = smem + 8192;
  const int bn = blockIdx.x, bm = blockIdx.y;
  const int tid = threadIdx.x;
  const int w = tid >> 6, lane = tid & 63;
  const int wm = w >> 1, wn = w & 1;
  const int c = lane & 15, g = lane >> 4;
  const int cl8 = c & 7;

  f32x4 acc[4][4];
#pragma unroll
  for (int i = 0; i < 4; ++i)
#pragma unroll
    for (int j = 0; j < 4; ++j) acc[i][j] = (f32x4){0.f, 0.f, 0.f, 0.f};

  const int srow = 32 * w + (lane >> 3);
  const int scol = 8 * ((lane & 7) ^ (lane >> 3));
  const unsigned short* Ag = A + (size_t)(bm * 128 + srow) * K + scol;
  const unsigned short* Bg = Bt + (size_t)(bn * 128 + srow) * K + scol;
  char* AsB = (char*)As + w * 4096;
  char* BsB = (char*)Bs + w * 4096;

  for (int kt = 0; kt < K / 64; ++kt) {
    const int kb = kt * 64;
    __syncthreads();
#pragma unroll
    for (int i = 0; i < 4; ++i) {
      gload16(Ag + (size_t)(8 * i) * K + kb, AsB + i * 1024);
      gload16(Bg + (size_t)(8 * i) * K + kb, BsB + i * 1024);
    }
    asm volatile("s_waitcnt vmcnt(0)" ::: "memory");
    __syncthreads();
#pragma unroll
    for (int u = 0; u < 2; ++u) {
      bf16x8 af[4], bfr[4];
#pragma unroll
      for (int mf = 0; mf < 4; ++mf)
        af[mf] = *(const bf16x8*)((const char*)As + (wm * 64 + mf * 16 + c) * 128 +
                                  (((u * 4 + g) ^ cl8) * 16));
#pragma unroll
      for (int nf = 0; nf < 4; ++nf)
        bfr[nf] = *(const bf16x8*)((const char*)Bs + (wn * 64 + nf * 16 + c) * 128 +
                                   (((u * 4 + g) ^ cl8) * 16));
#pragma unroll
      for (int mf = 0; mf < 4; ++mf)
#pragma unroll
        for (int nf = 0; nf < 4; ++nf)
          acc[mf][nf] = MFMA32(af[mf], bfr[nf], acc[mf][nf]);
    }
  }

  const int rowb = bm * 128 + wm * 64;
  const int colb = bn * 128 + wn * 64;
  if (EPI == 1) {
#pragma unroll
    for (int mf = 0; mf < 4; ++mf)
#pragma unroll
      for (int nf = 0; nf < 4; ++nf)
#pragma unroll
        for (int r = 0; r < 4; ++r) {
          int row = rowb + mf * 16 + 4 * g + r;
          int col = colb + nf * 16 + c;
          outF[(size_t)row * N + col] = acc[mf][nf][r];
        }
  } else {
    const int sec = colb >> 10;
    const int hh = (colb & 1023) >> 6;
    const int b = rowb >> 11, t0 = rowb & 2047;
    unsigned short* Lw = smem + w * 4096;

    __syncthreads();
    if (sec < 2) {
      const float sc = (sec == 0) ? 0.125f * 1.4426950408889634f : 1.f;
#pragma unroll
      for (int mf = 0; mf < 4; ++mf)
#pragma unroll
        for (int nf = 0; nf < 4; ++nf)
#pragma unroll
          for (int r = 0; r < 4; ++r)
            Lw[(16 * mf + 4 * g + r) * 64 + 16 * nf + c] = f2b(acc[mf][nf][r] * sc);
    } else {
#pragma unroll
      for (int mf = 0; mf < 4; ++mf)
#pragma unroll
        for (int nf = 0; nf < 4; ++nf)
#pragma unroll
          for (int rr = 0; rr < 2; ++rr)
            *(unsigned int*)&Lw[(16 * nf + c) * 64 + 16 * mf + 4 * g + 2 * rr] =
                pack2(acc[mf][nf][2 * rr], acc[mf][nf][2 * rr + 1]);
    }
    asm volatile("s_waitcnt lgkmcnt(0)" ::: "memory");
    const int rw = lane >> 3, ch = lane & 7;
    const int chx = ch ^ rw;
    if (sec == 0) {
      unsigned short* dst = q_ws + ((size_t)(b * 16 + hh) * 2048 + t0) * 64;
#pragma unroll
      for (int i = 0; i < 8; ++i) {
        int tl = i * 8 + rw;
        *(bf16x8*)(dst + (size_t)tl * 64 + ch * 8) = *(const bf16x8*)&Lw[tl * 64 + ch * 8];
      }
    } else if (sec == 1) {
      unsigned short* dst = k_ws + ((size_t)(b * 16 + hh) * 2048 + t0) * 64;
#pragma unroll
      for (int i = 0; i < 8; ++i) {
        int tl = i * 8 + rw;
        *(bf16x8*)(dst + (size_t)tl * 64 + chx * 8) = *(const bf16x8*)&Lw[tl * 64 + ch * 8];
      }
    } else {
      unsigned short* dst = v_ws + (size_t)(b * 16 + hh) * 64 * 2048 + t0;
#pragma unroll
      for (int i = 0; i < 8; ++i) {
        int dl = i * 8 + rw;
        *(bf16x8*)(dst + (size_t)dl * 2048 + chx * 8) = *(const bf16x8*)&Lw[dl * 64 + ch * 8];
      }
    }
  }
}

// ---------------------------------------------------------------------------
// Flash attention, causal. 512 blocks x 512 threads (8 waves).  R9 structure
// (best measured ~80us) + one graft: ALL 8 V-fragment ds_reads hoisted out of
// the PV h-loop to right after QK^T, so their LDS latency hides under the
// softmax VALU chain (mask/max/exp/pack) instead of stalling the PV MFMAs.
// ---------------------------------------------------------------------------
__global__ __launch_bounds__(512) void k_attn(const unsigned short* __restrict__ q_ws,
                                              const unsigned short* __restrict__ k_ws,
                                              const unsigned short* __restrict__ v_ws,
                                              unsigned short* __restrict__ y_ws) {
  constexpr int T = 2048;
  __shared__ unsigned short Ks[2][64 * 64];
  __shared__ unsigned short Vs[2][64 * 64];
  const int f = blockIdx.x;
  const int f2 = (f & 7) * 64 + (f >> 3);
  const int bh = f2 >> 3;
  const int xi = f2 & 7;
  const int tid = threadIdx.x, w = tid >> 6, lane = tid & 63;
  const int c = lane & 15, g = lane >> 4;
  const int cl = c & 7;
  const size_t base = (size_t)bh * T * 64;
  const unsigned short* Kb = k_ws + base;
  const unsigned short* Vb = v_ws + base;
  const unsigned short* Qb = q_ws + base;

  const int srow = w * 8 + (lane >> 3);
  const int sch = lane & 7;

#pragma unroll 1
  for (int ph = 0; ph < 2; ++ph) {
    const int q0 = (ph == 0 ? xi : 15 - xi) * 128;
    const int qrow = q0 + 16 * w + c;
    const int q_max_wave = q0 + 16 * w + 15;
    const int n_kt = (q0 >> 6) + 2;
    bf16x8 qf[2];
#pragma unroll
    for (int u = 0; u < 2; ++u)
      qf[u] = *(const bf16x8*)(Qb + (size_t)qrow * 64 + 32 * u + 8 * g);

    f32x4 yacc[4];
#pragma unroll
    for (int i = 0; i < 4; ++i) yacc[i] = (f32x4){0.f, 0.f, 0.f, 0.f};
    float m_run = -1e30f, l_part = 0.f;

    __syncthreads();  // prior phase fully done before restaging buf 0
    gload16(Kb + (size_t)srow * 64 + sch * 8, (char*)&Ks[0][0] + w * 1024);
    gload16(Vb + (size_t)srow * T + sch * 8, (char*)&Vs[0][0] + w * 1024);

#pragma unroll 1
    for (int kt = 0; kt < n_kt; ++kt) {
      const int k0 = kt * 64;
      const int cur = kt & 1;
      if (kt + 1 < n_kt) {
        const int k0n = k0 + 64;
        gload16(Kb + (size_t)(k0n + srow) * 64 + sch * 8, (char*)&Ks[cur ^ 1][0] + w * 1024);
        gload16(Vb + (size_t)srow * T + k0n + sch * 8, (char*)&Vs[cur ^ 1][0] + w * 1024);
        asm volatile("s_waitcnt vmcnt(2)" ::: "memory");
      } else {
        asm volatile("s_waitcnt vmcnt(0)" ::: "memory");
      }
      __builtin_amdgcn_s_barrier();

      if (k0 <= q_max_wave) {
        const char* KsC = (const char*)&Ks[cur][0];
        const char* VsC = (const char*)&Vs[cur][0];
        f32x4 s[4];
        __builtin_amdgcn_s_setprio(1);
#pragma unroll
        for (int tf = 0; tf < 4; ++tf) {
          bf16x8 kf0 = *(const bf16x8*)(KsC + (16 * tf + c) * 128 + (g ^ cl) * 16);
          bf16x8 kf1 = *(const bf16x8*)(KsC + (16 * tf + c) * 128 + ((4 + g) ^ cl) * 16);
          f32x4 z = (f32x4){0.f, 0.f, 0.f, 0.f};
          z = MFMA32(kf0, qf[0], z);
          s[tf] = MFMA32(kf1, qf[1], z);
        }
        __builtin_amdgcn_s_setprio(0);
        // V-frag prefetch (same addresses/values as the PV loop used; hoisted
        // so LDS latency overlaps the softmax VALU below)
        bf16x8 vf[2][4];
#pragma unroll
        for (int h = 0; h < 2; ++h)
#pragma unroll
          for (int df = 0; df < 4; ++df)
            vf[h][df] = *(const bf16x8*)(VsC + (16 * df + c) * 128 + ((h * 4 + g) ^ cl) * 16);
        if (k0 + 63 > q0 + 16 * w) {
#pragma unroll
          for (int tf = 0; tf < 4; ++tf)
#pragma unroll
            for (int r = 0; r < 4; ++r)
              if (k0 + 16 * tf + 4 * g + r > qrow) s[tf][r] = -1e30f;
        }
        float mx0 = fmaxf(fmaxf(s[0][0], s[0][1]), fmaxf(s[0][2], s[0][3]));
        float mx1 = fmaxf(fmaxf(s[1][0], s[1][1]), fmaxf(s[1][2], s[1][3]));
        float mx2 = fmaxf(fmaxf(s[2][0], s[2][1]), fmaxf(s[2][2], s[2][3]));
        float mx3 = fmaxf(fmaxf(s[3][0], s[3][1]), fmaxf(s[3][2], s[3][3]));
        float mx = fmaxf(fmaxf(mx0, mx1), fmaxf(mx2, mx3));
        mx = fmaxf(mx, __shfl_xor(mx, 16));
        mx = fmaxf(mx, __shfl_xor(mx, 32));
        if (__any(mx > m_run + 11.5f)) {
          float m_new = fmaxf(m_run, mx);
          float corr = exp2v(m_run - m_new);
          l_part *= corr;
#pragma unroll
          for (int i = 0; i < 4; ++i) yacc[i] *= corr;
          m_run = m_new;
        }
        float p[16];
#pragma unroll
        for (int tf = 0; tf < 4; ++tf)
#pragma unroll
          for (int r = 0; r < 4; ++r) p[tf * 4 + r] = exp2v(s[tf][r] - m_run);
        float ps = ((p[0] + p[1]) + (p[2] + p[3])) + ((p[4] + p[5]) + (p[6] + p[7]));
        ps += ((p[8] + p[9]) + (p[10] + p[11])) + ((p[12] + p[13]) + (p[14] + p[15]));
        l_part += ps;

#pragma unroll
        for (int h = 0; h < 2; ++h) {
          unsigned int lo0 = cvtpk(p[8 * h + 0], p[8 * h + 1]);
          unsigned int hi0 = cvtpk(p[8 * h + 2], p[8 * h + 3]);
          unsigned int lo1 = cvtpk(p[8 * h + 4], p[8 * h + 5]);
          unsigned int hi1 = cvtpk(p[8 * h + 6], p[8 * h + 7]);
          int a2 = 2 * (g & 1);
          int srcA = 16 * a2 + c, srcB = srcA + 16;
          unsigned int Al0 = __shfl(lo0, srcA), Ah0 = __shfl(hi0, srcA);
          unsigned int Al1 = __shfl(lo1, srcA), Ah1 = __shfl(hi1, srcA);
          unsigned int Bl0 = __shfl(lo0, srcB), Bh0 = __shfl(hi0, srcB);
          unsigned int Bl1 = __shfl(lo1, srcB), Bh1 = __shfl(hi1, srcB);
          bool f1 = (g >= 2);
          union { unsigned int u[4]; bf16x8 v; } pf;
          pf.u[0] = f1 ? Al1 : Al0;
          pf.u[1] = f1 ? Ah1 : Ah0;
          pf.u[2] = f1 ? Bl1 : Bl0;
          pf.u[3] = f1 ? Bh1 : Bh0;
          __builtin_amdgcn_s_setprio(1);
#pragma unroll
          for (int df = 0; df < 4; ++df)
            yacc[df] = MFMA32(vf[h][df], pf.v, yacc[df]);
          __builtin_amdgcn_s_setprio(0);
        }
      }
      __builtin_amdgcn_s_barrier();
    }

    float lt = l_part;
    lt += __shfl_xor(lt, 16);
    lt += __shfl_xor(lt, 32);
    float inv = 1.f / lt;
    const int b = bh >> 4, hh = bh & 15;
#pragma unroll
    for (int df = 0; df < 4; ++df) {
      uint2 o;
      o.x = cvtpk(yacc[df][0] * inv, yacc[df][1] * inv);
      o.y = cvtpk(yacc[df][2] * inv, yacc[df][3] * inv);
      *(uint2*)(y_ws + (size_t)(b * 2048 + qrow) * 1024 + hh * 64 + 16 * df + 4 * g) = o;
    }
  }
}

// ---------------------------------------------------------------------------
extern "C" void kernel_launch(void* const* d_in, const int* in_sizes, int n_in,
                              void* d_out, int out_size, void* d_ws, size_t ws_size,
                              hipStream_t stream) {
  const float* x = (const float*)d_in[0];      // (4, 2048, 1024)
  const float* Wqkv = (const float*)d_in[1];   // (1024, 3072)
  const float* Wproj = (const float*)d_in[2];  // (1024, 1024)
  float* out = (float*)d_out;                  // (4, 2048, 1024)
  char* ws = (char*)d_ws;

  unsigned short* x_bf = (unsigned short*)(ws);                    // 16 MiB
  unsigned short* wqkvT = (unsigned short*)(ws + 16777216);        // 6 MiB
  unsigned short* wprojT = (unsigned short*)(ws + 23068672);       // 2 MiB
  unsigned short* q_ws = (unsigned short*)(ws + 25165824);         // 16 MiB
  unsigned short* k_ws = (unsigned short*)(ws + 41943040);         // 16 MiB
  unsigned short* v_ws = (unsigned short*)(ws + 58720256);         // 16 MiB
  unsigned short* y_ws = (unsigned short*)(ws + 75497472);         // 16 MiB

  k_conv_x<<<8192, 256, 0, stream>>>(x, x_bf, 2097152);
  k_transpose<<<dim3(96, 32), 256, 0, stream>>>(Wqkv, wqkvT, 1024, 3072);
  k_transpose<<<dim3(32, 32), 256, 0, stream>>>(Wproj, wprojT, 1024, 1024);
  k_gemm<0><<<dim3(24, 64), 256, 0, stream>>>(x_bf, wqkvT, nullptr, q_ws, k_ws, v_ws, 8192, 3072);
  k_attn<<<512, 512, 0, stream>>>(q_ws, k_ws, v_ws, y_ws);
  k_gemm<1><<<dim3(8, 64), 256, 0, stream>>>(y_ws, wprojT, out, nullptr, nullptr, nullptr, 8192, 1024);
}